// Round 1
// baseline (436.724 us; speedup 1.0000x reference)
//
#include <hip/hip_runtime.h>

#define B_ 256
#define K_ 512
#define D_ 256
#define H_ 256
#define NROWS (B_*K_)          // 131072
#define RPB 64                 // rows per block
#define LNEPS 1e-5f

// Block = 512 threads = 8 waves. Each block handles 64 rows.
// Phase 1: LayerNorm -> LDS xln[64][256] (xor-swizzled, 64 KB exactly).
// Phase 2: wave w computes cols [32w,32w+32) for all 64 rows (lane = row).
//          w1 values are wave-uniform -> scalar loads (SGPR operand FMA).
__global__ __launch_bounds__(512, 4) void fused_main(
    const float* __restrict__ slots, const float* __restrict__ gamma,
    const float* __restrict__ beta,  const float* __restrict__ w1,
    const float* __restrict__ b1,    const float* __restrict__ w2,
    const float* __restrict__ b2,    const float* __restrict__ u,
    float* __restrict__ out)
{
    __shared__ float smem[RPB * D_];   // 65536 B
    const int t = threadIdx.x;
    const int row0 = blockIdx.x * RPB;

    // ---------------- Phase 1: LayerNorm ----------------
    {
        const int row = t >> 3;    // 0..63 (8 consecutive threads per row, same wave)
        const int oct = t & 7;     // 0..7, covers 32 d's each
        const float* sp = slots + (size_t)(row0 + row) * D_ + oct * 32;
        float x[32];
        #pragma unroll
        for (int i = 0; i < 8; ++i) {
            float4 v = ((const float4*)sp)[i];
            x[4*i+0] = v.x; x[4*i+1] = v.y; x[4*i+2] = v.z; x[4*i+3] = v.w;
        }
        float s = 0.f;
        #pragma unroll
        for (int i = 0; i < 32; ++i) s += x[i];
        s += __shfl_xor(s, 1, 64);
        s += __shfl_xor(s, 2, 64);
        s += __shfl_xor(s, 4, 64);
        const float mean = s * (1.f/256.f);
        float vs = 0.f;
        #pragma unroll
        for (int i = 0; i < 32; ++i) { float dx = x[i] - mean; vs += dx*dx; }
        vs += __shfl_xor(vs, 1, 64);
        vs += __shfl_xor(vs, 2, 64);
        vs += __shfl_xor(vs, 4, 64);
        const float rstd = rsqrtf(vs * (1.f/256.f) + LNEPS);
        const int swz = (row & 7) << 2;
        #pragma unroll
        for (int i = 0; i < 8; ++i) {
            const int d  = oct*32 + i*4;
            const int pd = (d & ~31) | ((d & 31) ^ swz);   // xor-swizzle, 4-float granular
            float4 gv = *(const float4*)(gamma + d);
            float4 bv = *(const float4*)(beta  + d);
            float4 o;
            o.x = (x[4*i+0]-mean)*rstd*gv.x + bv.x;
            o.y = (x[4*i+1]-mean)*rstd*gv.y + bv.y;
            o.z = (x[4*i+2]-mean)*rstd*gv.z + bv.z;
            o.w = (x[4*i+3]-mean)*rstd*gv.w + bv.w;
            *(float4*)&smem[row*D_ + pd] = o;
        }
    }
    __syncthreads();

    // ---------------- Phase 2: GEMM (lane = row, scalar w1) ----------------
    const int lane = t & 63;
    const int wv   = __builtin_amdgcn_readfirstlane(t >> 6);  // 0..7, uniform
    const int cb   = wv * 32;                                 // col base
    float acc[32];
    #pragma unroll
    for (int j = 0; j < 32; ++j) acc[j] = b1[cb + j];         // uniform -> s_load

    const int swz2 = (lane & 7) << 2;
    const float* w1p = w1 + cb;
    for (int d0 = 0; d0 < D_; d0 += 4) {
        const int pd = (d0 & ~31) | ((d0 & 31) ^ swz2);
        const float4 xv = *(const float4*)&smem[lane*D_ + pd];
        #pragma unroll
        for (int dd = 0; dd < 4; ++dd) {
            const float xd = (dd==0) ? xv.x : (dd==1) ? xv.y : (dd==2) ? xv.z : xv.w;
            const float* wrow = w1p + (size_t)(d0 + dd) * H_;  // uniform address
            #pragma unroll
            for (int j = 0; j < 32; ++j)
                acc[j] = fmaf(xd, wrow[j], acc[j]);
        }
    }

    // ---------------- Epilogue: relu, w2 reduce, gumbel ----------------
    float p0 = 0.f, p1 = 0.f;
    #pragma unroll
    for (int j = 0; j < 32; ++j) {
        const float r = fmaxf(acc[j], 0.f);
        p0 = fmaf(r, w2[(cb + j)*2 + 0], p0);   // uniform -> s_load
        p1 = fmaf(r, w2[(cb + j)*2 + 1], p1);
    }
    __syncthreads();                 // xln dead; reuse smem as partial buffer
    smem[(wv*64 + lane)*2 + 0] = p0;
    smem[(wv*64 + lane)*2 + 1] = p1;
    __syncthreads();
    if (t < 64) {
        float l0 = b2[0], l1 = b2[1];
        #pragma unroll
        for (int w = 0; w < 8; ++w) {
            l0 += smem[(w*64 + t)*2 + 0];
            l1 += smem[(w*64 + t)*2 + 1];
        }
        const int gr = row0 + t;
        const float u0 = u[2*gr + 0];
        const float u1 = u[2*gr + 1];
        const float g0 = -logf(-logf(u0));
        const float g1 = -logf(-logf(u1));
        const float mask = ((l1 + g1) > (l0 + g0)) ? 1.f : 0.f;
        const float soft = 1.f / (1.f + expf(l0 - l1));   // softmax(logits)[1]
        out[gr] = mask;
        out[NROWS + gr] = soft;
    }
}

// Lower-bound fixup: per batch row b, if no slot kept, set mask=1 at the
// dropped slot with max rand_key (first index on ties, matching stable argsort).
__global__ __launch_bounds__(512) void fixup(
    const float* __restrict__ rk, float* __restrict__ out)
{
    __shared__ unsigned long long best[8];
    __shared__ int cnts[8];
    const int b = blockIdx.x;
    const int k = threadIdx.x;              // 0..511
    const float m = out[b*K_ + k];
    const unsigned long long ball = __ballot(m != 0.f);
    const int wv = k >> 6;
    const int wcount = __popcll(ball);
    const unsigned kb = __float_as_uint(rk[b*K_ + k]);   // positive floats: bits monotone
    unsigned long long comb = ((unsigned long long)kb << 32) | (unsigned)(K_ - 1 - k);
    #pragma unroll
    for (int off = 32; off; off >>= 1) {
        unsigned long long o = __shfl_down(comb, off, 64);
        if (o > comb) comb = o;
    }
    if ((k & 63) == 0) { best[wv] = comb; cnts[wv] = wcount; }
    __syncthreads();
    if (k == 0) {
        int tot = 0; unsigned long long bc = 0;
        #pragma unroll
        for (int w = 0; w < 8; ++w) { tot += cnts[w]; if (best[w] > bc) bc = best[w]; }
        if (tot == 0) {
            const int kbest = (K_ - 1) - (int)(bc & 0xffffffffu);
            out[b*K_ + kbest] = 1.f;
        }
    }
}

extern "C" void kernel_launch(void* const* d_in, const int* in_sizes, int n_in,
                              void* d_out, int out_size, void* d_ws, size_t ws_size,
                              hipStream_t stream) {
    const float* slots = (const float*)d_in[0];
    const float* gamma = (const float*)d_in[1];
    const float* beta  = (const float*)d_in[2];
    const float* w1    = (const float*)d_in[3];
    const float* b1    = (const float*)d_in[4];
    const float* w2    = (const float*)d_in[5];
    const float* b2    = (const float*)d_in[6];
    const float* u     = (const float*)d_in[7];
    const float* rk    = (const float*)d_in[8];
    float* out = (float*)d_out;

    hipLaunchKernelGGL(fused_main, dim3(NROWS / RPB), dim3(512), 0, stream,
                       slots, gamma, beta, w1, b1, w2, b2, u, out);
    hipLaunchKernelGGL(fixup, dim3(B_), dim3(512), 0, stream, rk, out);
}